// Round 3
// 267.867 us; speedup vs baseline: 1.1237x; 1.1237x over previous
//
#include <hip/hip_runtime.h>
#include <stdint.h>

#define ROUNDS 64
#define HIDDEN 256
#define BATCH  65536

typedef int   v4i  __attribute__((ext_vector_type(4)));
typedef int   v8i  __attribute__((ext_vector_type(8)));
typedef float v16f __attribute__((ext_vector_type(16)));

// ws layout: Wpk fp4 fragments [r][mt=8][ks=4][lane=64][16B] = 2 MB,
// then noise floats [r][wv=8][lh=2][j=16] f32 = 64 KB.
#define WPK_BYTES (ROUNDS * 8 * 4 * 64 * 16)

// sigma: nibble slot n (0..31) within a 32-k chunk holds logical k-offset
// rho(n). Rows (j&3)+8*(j>>2)+4*lh of the 32x32 C layout land in each lane's
// own contiguous 8 bytes -> 1 conflict-free ds_write_b64 epilogue. Applied
// identically to W-pack, state init, and unpack, so it cancels in the dot.
__host__ __device__ constexpr int rho(int n) {
  return 4 * (n >> 4) + (n & 3) + 8 * ((n >> 2) & 3);
}

// Per-C-slot bias, applied in the EPILOGUE (plain v_add_f32 — IEEE exact for
// value+1.5*2^{22-4q}: result stays in [2^e, 2^(e+1)), value is an integer,
// ulp <= 0.5). NOTE round-1 FAILED experiment: folding these biases into the
// MFMA C-init gave absmax 1.0 — consistent with the f8f6f4 MFMA aligning dot
// addends to the max exponent with a limited window, flushing the +-1
// products against a 2^22 C. Bias must stay OUTSIDE the MFMA.
// Slot j (q = j&3) gets 1.5*2^{22-4q} -> parity bit lands at mantissa bit
// 23-e = 4q+1, i.e. exactly the fp4-nibble bit-1 position for nibble q.
__host__ __device__ constexpr float bias_q(int q) {
  return (q == 0) ? 6291456.0f   // 1.5*2^22 -> parity at bit 1
       : (q == 1) ? 393216.0f    // 1.5*2^18 -> bit 5
       : (q == 2) ? 24576.0f     // 1.5*2^14 -> bit 9
                  : 1536.0f;     // 1.5*2^10 -> bit 13
}

// ---- pack W into fp4 A-fragments (blocks 0..511) and noise->f32 in
// C-layout row order (blocks 512..575) ----
__global__ __launch_bounds__(256) void pack_w4(const float* __restrict__ mat,
                                               const float* __restrict__ noi,
                                               uint32_t* __restrict__ wpk,
                                               float* __restrict__ nf) {
  if (blockIdx.x >= 512) {  // noise: nf[r][wv][lh][j] = noise[r][row(j,lh)+wv*32]
    unsigned tg = (blockIdx.x - 512) * 256u + threadIdx.x;  // < 16384
    unsigned j = tg & 15u, lh = (tg >> 4) & 1u, wv = (tg >> 5) & 7u, r = tg >> 8;
    unsigned row = wv * 32u + (j & 3u) + 8u * (j >> 2) + 4u * lh;
    nf[tg] = noi[r * 256u + row];
    return;
  }
  unsigned tg = blockIdx.x * 256u + threadIdx.x;  // (r*256+row)*8 + kwin
  unsigned kwin = tg & 7u;
  unsigned rr = tg >> 3;  // r*256 + row
  const float4* F4 = (const float4*)(mat + (size_t)rr * 256 + kwin * 32);
  float4 F[8];
#pragma unroll
  for (int i = 0; i < 8; ++i) F[i] = F4[i];
  const float* Ff = (const float*)F;
  uint32_t w[4] = {0, 0, 0, 0};
#pragma unroll
  for (int n = 0; n < 32; ++n) {
    uint32_t u = __builtin_bit_cast(uint32_t, Ff[rho(n)]);
    // fp4 e2m1: 0 -> 0b0000, +1 -> 0b0010, -1 -> 0b1010
    uint32_t nib = ((u & 0x7fffffffu) ? 2u : 0u) | ((u >> 28) & 8u);
    w[n >> 3] |= nib << ((n & 7) * 4);
  }
  unsigned r = rr >> 8, row = rr & 255u;
  unsigned mt = row >> 5, lh = kwin & 1u, ks = kwin >> 1;
  unsigned lane = lh * 32u + (row & 31u);
  *(uint4*)(wpk + ((((r * 8u + mt) * 4u + ks) * 64u + lane) << 2)) =
      make_uint4(w[0], w[1], w[2], w[3]);
}

// ---- main: 128 el/block, 8 waves; wave wv = rows [wv*32, wv*32+32) for all
// 128 elements. fp4 MFMA 32x32x64, K=256 in 4 steps, noise as MFMA C-init,
// per-slot bias-trick epilogue. State double-buffered in LDS
// [buf][KB=8][el=128][16B].
// NOTE: barrier is __syncthreads() — the raw lgkm-only s_barrier variant
// produced warm-state-dependent divergence (round-5 FAILED experiment).
__global__ __launch_bounds__(512, 4) void hash4(const uint32_t* __restrict__ wpk,
                                                const float* __restrict__ nf,
                                                const float* __restrict__ sta,
                                                float* __restrict__ out) {
  __shared__ uint8_t T[2][8][128][16];  // 32 KB
  const int t = threadIdx.x;
  const int wv = __builtin_amdgcn_readfirstlane(t >> 6);  // m-tile 0..7
  const int lane = t & 63;
  const int l31 = lane & 31;
  const int lh = lane >> 5;
  const int el0 = blockIdx.x * 128;

  // ---- initial pack: f32 -> sigma-ordered fp4 nibbles (4 logical k per u16) ----
#pragma unroll
  for (int i = 0; i < 16; ++i) {
    unsigned flat = (unsigned)i * 512u + t;  // float4 idx in 128x256 slab
    unsigned el = flat >> 6, k4 = flat & 63u;
    float4 f = ((const float4*)(sta + (size_t)el0 * 256))[flat];
    uint32_t v = ((f.x != 0.f) ? 0x2u : 0u) | ((f.y != 0.f) ? 0x20u : 0u) |
                 ((f.z != 0.f) ? 0x200u : 0u) | ((f.w != 0.f) ? 0x2000u : 0u);
    unsigned KB = k4 >> 3, k4c = k4 & 7u;
    unsigned byteoff = (k4c & 1u) * 8u + 2u * (k4c >> 1);  // sigma^-1 of 4 rows
    *(uint16_t*)&T[0][KB][el][byteoff] = (uint16_t)v;
  }
  __syncthreads();

  // prefetch round-0 A fragments + noise C-init
  v4i ap[4];
  {
    const uint32_t* wb = wpk + ((wv * 4) << 8);
#pragma unroll
    for (int ks = 0; ks < 4; ++ks) ap[ks] = *(const v4i*)(wb + ks * 256 + lane * 4);
  }
  v16f NZ = *(const v16f*)(nf + (wv * 2 + lh) * 16);

  for (int r = 0; r < ROUNDS; ++r) {
    const int rb = r & 1, nx = rb ^ 1;
    v16f acc[4];
    __builtin_amdgcn_s_setprio(1);
#pragma unroll
    for (int ks = 0; ks < 4; ++ks) {
      // fp4 fmt uses only regs 0..3 of the 8-reg operand: leave 4..7 undef
      // (no zero-materializing v_movs).
      v8i A8 = __builtin_shufflevector(ap[ks], ap[ks], 0, 1, 2, 3, -1, -1, -1, -1);
      const int kb = 2 * ks + lh;
#pragma unroll
      for (int tn = 0; tn < 4; ++tn) {
        v4i b4 = *(const v4i*)&T[rb][kb][tn * 32 + l31][0];  // conflict-free b128
        v8i B8 = __builtin_shufflevector(b4, b4, 0, 1, 2, 3, -1, -1, -1, -1);
        acc[tn] = __builtin_amdgcn_mfma_scale_f32_32x32x64_f8f6f4(
            A8, B8, (ks == 0) ? NZ : acc[tn], 4, 4, 0, 127, 0, 127);
      }
    }
    __builtin_amdgcn_s_setprio(0);

    // prefetch next round's A + noise (r=63 wraps to 0 -> no OOB, dead value)
    {
      const int rn = (r + 1) & 63;
      const uint32_t* wb = wpk + (((rn * 8 + wv) * 4) << 8);
#pragma unroll
      for (int ks = 0; ks < 4; ++ks) ap[ks] = *(const v4i*)(wb + ks * 256 + lane * 4);
      NZ = *(const v16f*)(nf + ((rn * 8 + wv) * 2 + lh) * 16);
    }

    // epilogue: per-slot bias (v_add_f32, exact) puts slot j's parity bit at
    // mantissa bit 4*(j&3)+1 == its target nibble-bit. Extraction is then a
    // mask + or-chain (v_and_b32 / v_and_or_b32), no shifts except one <<16
    // merge per word.
#pragma unroll
    for (int tn = 0; tn < 4; ++tn) {
#define PB(j)                                                          \
  (__builtin_bit_cast(uint32_t, acc[tn][j] + bias_q((j) & 3)) &        \
   (2u << (4 * ((j) & 3))))
      uint32_t u0 = PB(0) | PB(1) | PB(2) | PB(3);
      uint32_t u1 = PB(4) | PB(5) | PB(6) | PB(7);
      uint32_t u2 = PB(8) | PB(9) | PB(10) | PB(11);
      uint32_t u3 = PB(12) | PB(13) | PB(14) | PB(15);
#undef PB
      *(uint2*)&T[nx][wv][tn * 32 + l31][lh * 8] =
          make_uint2(u0 | (u1 << 16), u2 | (u3 << 16));
    }

    __syncthreads();  // single barrier/round (double-buffered state)
  }

  // ---- final unpack: buf 0 holds the round-63 output ----
#pragma unroll
  for (int i = 0; i < 16; ++i) {
    unsigned flat = (unsigned)i * 512u + t;
    unsigned el = flat >> 6, k4 = flat & 63u;
    unsigned KB = k4 >> 3, k4c = k4 & 7u;
    unsigned byteoff = (k4c & 1u) * 8u + 2u * (k4c >> 1);
    uint32_t v = *(const uint16_t*)&T[0][KB][el][byteoff];
    float4 o = make_float4((float)((v >> 1) & 1u), (float)((v >> 5) & 1u),
                           (float)((v >> 9) & 1u), (float)((v >> 13) & 1u));
    ((float4*)(out + (size_t)el0 * 256))[flat] = o;
  }
}

extern "C" void kernel_launch(void* const* d_in, const int* in_sizes, int n_in,
                              void* d_out, int out_size, void* d_ws, size_t ws_size,
                              hipStream_t stream) {
  const float* sta = (const float*)d_in[0];  // [B, HIDDEN]
  const float* mat = (const float*)d_in[1];  // [ROUNDS, HIDDEN, HIDDEN]
  const float* noi = (const float*)d_in[2];  // [ROUNDS, HIDDEN]
  uint8_t* wsb = (uint8_t*)d_ws;             // needs ~2.07 MB

  pack_w4<<<576, 256, 0, stream>>>(mat, noi, (uint32_t*)wsb,
                                   (float*)(wsb + WPK_BYTES));
  hash4<<<512, 512, 0, stream>>>((const uint32_t*)wsb,
                                 (const float*)(wsb + WPK_BYTES), sta,
                                 (float*)d_out);
}